// Round 1
// baseline (5009.082 us; speedup 1.0000x reference)
//
#include <hip/hip_runtime.h>
#include <hip/hip_fp16.h>

constexpr float ALPHA = 0.9f;
constexpr float DT    = 0.1f;
constexpr int BB   = 256;   // batch
constexpr int NIN  = 784;
constexpr int NN   = 1024;
constexpr int LL   = 4;
constexpr int NOUT = 10;
constexpr int TT   = 100;

typedef _Float16 f16x8 __attribute__((ext_vector_type(8)));
typedef _Float16 f16x4 __attribute__((ext_vector_type(4)));
typedef float    f32x4 __attribute__((ext_vector_type(4)));

// ---------------- weight fp32 -> fp16 conversion ----------------
__global__ void wconv_kernel(const float* __restrict__ Wrec,
                             const float* __restrict__ Win,
                             _Float16* __restrict__ Wrec_h,
                             _Float16* __restrict__ Win_h) {
    size_t i = (size_t)blockIdx.x * blockDim.x + threadIdx.x;  // 0 .. 1048575
    float4 r = ((const float4*)Wrec)[i];
    float4 n = ((const float4*)Win)[i];
    f16x4 rh = {(_Float16)r.x, (_Float16)r.y, (_Float16)r.z, (_Float16)r.w};
    f16x4 nh = {(_Float16)n.x, (_Float16)n.y, (_Float16)n.z, (_Float16)n.w};
    ((f16x4*)Wrec_h)[i] = rh;
    ((f16x4*)Win_h)[i]  = nh;
}

// ---------------- combined bias: bc[l] = Wrec_b[l] (+ Win_b[l] for l>0) ----
__global__ void bias_kernel(const float* __restrict__ Win_b,
                            const float* __restrict__ Wrec_b,
                            float* __restrict__ bc) {
    int i = blockIdx.x * 256 + threadIdx.x;  // 0..4095
    int l = i >> 10;
    float v = Wrec_b[i];
    if (l > 0) v += Win_b[i];
    bc[i] = v;
}

// ---------------- x_in = X @ Wi_w^T + Wi_b  (fp32, exact) ----------------
__global__ void xin_kernel(const float* __restrict__ X,
                           const float* __restrict__ Wi_w,
                           const float* __restrict__ Wi_b,
                           float* __restrict__ x_in) {
    __shared__ __align__(16) float xr[NIN];
    int i = blockIdx.x;
    for (int k = threadIdx.x; k < NIN; k += 256) xr[k] = X[(size_t)i * NIN + k];
    __syncthreads();
    for (int j = threadIdx.x; j < NN; j += 256) {
        const float4* w4 = (const float4*)(Wi_w + (size_t)j * NIN);
        float s0 = 0.f, s1 = 0.f, s2 = 0.f, s3 = 0.f;
        #pragma unroll 4
        for (int k4 = 0; k4 < NIN / 4; ++k4) {
            float4 w  = w4[k4];
            float4 xv = *(const float4*)(xr + k4 * 4);
            s0 += w.x * xv.x; s1 += w.y * xv.y;
            s2 += w.z * xv.z; s3 += w.w * xv.w;
        }
        x_in[(size_t)i * NN + j] = (s0 + s1) + (s2 + s3) + Wi_b[j];
    }
}

// ---------------- wavefront stage: update all active (l, t=s-l) ----------
// Hf: [2][4][256][1024] fp32 state, Hh: same shape fp16 shadow (MFMA operand).
// parity: state after step t lives at parity (t+1)&1; initial state parity 0.
__global__ __launch_bounds__(256) void stage_kernel(
    int s,
    const _Float16* __restrict__ Wrec_h,
    const _Float16* __restrict__ Win_h,
    const float* __restrict__ bc,
    const float* __restrict__ x_in,
    float* __restrict__ Hf,
    _Float16* __restrict__ Hh) {
    const int b  = blockIdx.x;
    const int l  = (b & 7) >> 1;              // layer -> XCD pair (b%8)
    const int il = ((b >> 3) << 1) | (b & 1); // 0..127 tile index within layer
    const int t  = s - l;
    if (t < 0 || t >= TT) return;

    const int src = t & 1, dst = src ^ 1;
    const size_t HSZ = (size_t)BB * NN;
    const float*    hold_f = Hf + ((size_t)src * LL + l) * HSZ;
    float*          hnew_f = Hf + ((size_t)dst * LL + l) * HSZ;
    _Float16*       hnew_h = Hh + ((size_t)dst * LL + l) * HSZ;
    const _Float16* a_rec  = Hh + ((size_t)src * LL + l) * HSZ;
    const _Float16* Wr     = Wrec_h + (size_t)l * NN * NN;

    const int lane = threadIdx.x & 63;
    const int wave = threadIdx.x >> 6;
    const int lm   = lane & 15;
    const int kg   = lane >> 4;
    const int row0 = (il >> 3) * 16;              // 16 row tiles
    const int col0 = (il & 7) * 128 + wave * 32;  // 8 col tiles x 4 waves

    f32x4 acc0 = {0.f, 0.f, 0.f, 0.f};
    f32x4 acc1 = {0.f, 0.f, 0.f, 0.f};

    const _Float16* ap  = a_rec + (size_t)(row0 + lm) * NN + kg * 8;
    const _Float16* b0p = Wr + (size_t)(col0 + lm) * NN + kg * 8;
    const _Float16* b1p = Wr + (size_t)(col0 + 16 + lm) * NN + kg * 8;

    if (l == 0) {
        #pragma unroll 4
        for (int k = 0; k < NN; k += 32) {
            f16x8 a  = *(const f16x8*)(ap + k);
            f16x8 b0 = *(const f16x8*)(b0p + k);
            f16x8 b1 = *(const f16x8*)(b1p + k);
            acc0 = __builtin_amdgcn_mfma_f32_16x16x32_f16(a, b0, acc0, 0, 0, 0);
            acc1 = __builtin_amdgcn_mfma_f32_16x16x32_f16(a, b1, acc1, 0, 0, 0);
        }
    } else {
        const _Float16* a_in = Hh + ((size_t)dst * LL + (l - 1)) * HSZ;
        const _Float16* Wn   = Win_h + (size_t)l * NN * NN;
        const _Float16* cp  = a_in + (size_t)(row0 + lm) * NN + kg * 8;
        const _Float16* d0p = Wn + (size_t)(col0 + lm) * NN + kg * 8;
        const _Float16* d1p = Wn + (size_t)(col0 + 16 + lm) * NN + kg * 8;
        #pragma unroll 2
        for (int k = 0; k < NN; k += 32) {
            f16x8 a  = *(const f16x8*)(ap + k);
            f16x8 b0 = *(const f16x8*)(b0p + k);
            f16x8 b1 = *(const f16x8*)(b1p + k);
            f16x8 c  = *(const f16x8*)(cp + k);
            f16x8 d0 = *(const f16x8*)(d0p + k);
            f16x8 d1 = *(const f16x8*)(d1p + k);
            acc0 = __builtin_amdgcn_mfma_f32_16x16x32_f16(a, b0, acc0, 0, 0, 0);
            acc1 = __builtin_amdgcn_mfma_f32_16x16x32_f16(a, b1, acc1, 0, 0, 0);
            acc0 = __builtin_amdgcn_mfma_f32_16x16x32_f16(c, d0, acc0, 0, 0, 0);
            acc1 = __builtin_amdgcn_mfma_f32_16x16x32_f16(c, d1, acc1, 0, 0, 0);
        }
    }

    // epilogue: pre = acc + bias (+x_in for l==0); h' = h + DT*(-ALPHA*h + sin(pre))
    const float* bcl = bc + l * NN;
    #pragma unroll
    for (int r = 0; r < 4; ++r) {
        int row = row0 + kg * 4 + r;  // verified C/D layout: col=lane&15, row=(lane>>4)*4+reg
        #pragma unroll
        for (int cc = 0; cc < 2; ++cc) {
            int col = col0 + cc * 16 + lm;
            size_t idx = (size_t)row * NN + col;
            float pre = (cc ? acc1[r] : acc0[r]) + bcl[col];
            if (l == 0) pre += x_in[idx];
            float hold = hold_f[idx];
            float hnew = hold + DT * (-ALPHA * hold + sinf(pre));
            hnew_f[idx] = hnew;
            hnew_h[idx] = (_Float16)hnew;
        }
    }
}

// ---------------- out = h[3] @ Wo^T + Wo_b  (fp32) ----------------
__global__ void out_kernel(const float* __restrict__ Hf,
                           const float* __restrict__ Wo_w,
                           const float* __restrict__ Wo_b,
                           float* __restrict__ out) {
    // final state (after t=99) at parity (99+1)&1 = 0, layer 3
    const float* h = Hf + ((size_t)0 * LL + 3) * (size_t)BB * NN + (size_t)blockIdx.x * NN;
    int lane = threadIdx.x;
    for (int j = 0; j < NOUT; ++j) {
        const float* w = Wo_w + (size_t)j * NN;
        float s = 0.f;
        for (int k = lane; k < NN; k += 64) s += h[k] * w[k];
        #pragma unroll
        for (int off = 32; off; off >>= 1) s += __shfl_down(s, off);
        if (lane == 0) out[blockIdx.x * NOUT + j] = s + Wo_b[j];
    }
}

extern "C" void kernel_launch(void* const* d_in, const int* in_sizes, int n_in,
                              void* d_out, int out_size, void* d_ws, size_t ws_size,
                              hipStream_t stream) {
    const float* X      = (const float*)d_in[0];
    const float* Wi_w   = (const float*)d_in[1];
    const float* Wi_b   = (const float*)d_in[2];
    const float* Win_w  = (const float*)d_in[3];
    const float* Win_b  = (const float*)d_in[4];
    const float* Wrec_w = (const float*)d_in[5];
    const float* Wrec_b = (const float*)d_in[6];
    const float* Wo_w   = (const float*)d_in[7];
    const float* Wo_b   = (const float*)d_in[8];
    // d_in[9] = T (always 100; graph is static anyway)

    char* ws = (char*)d_ws;
    _Float16* Wrec_h = (_Float16*)(ws);                        // 8 MB
    _Float16* Win_h  = (_Float16*)(ws + (size_t)(8u  << 20));  // 8 MB
    float*    Hf     = (float*)   (ws + (size_t)(16u << 20));  // 8 MB
    _Float16* Hh     = (_Float16*)(ws + (size_t)(24u << 20));  // 4 MB
    float*    x_in   = (float*)   (ws + (size_t)(28u << 20));  // 1 MB
    float*    bc     = (float*)   (ws + (size_t)(29u << 20));  // 16 KB

    wconv_kernel<<<4096, 256, 0, stream>>>(Wrec_w, Win_w, Wrec_h, Win_h);
    bias_kernel<<<16, 256, 0, stream>>>(Win_b, Wrec_b, bc);
    xin_kernel<<<256, 256, 0, stream>>>(X, Wi_w, Wi_b, x_in);
    // zero parity-0 state (initial h = 0)
    hipMemsetAsync(Hf, 0, (size_t)LL * BB * NN * sizeof(float), stream);
    hipMemsetAsync(Hh, 0, (size_t)LL * BB * NN * sizeof(_Float16), stream);

    for (int s = 0; s <= TT + LL - 2; ++s)
        stage_kernel<<<dim3(512), dim3(256), 0, stream>>>(s, Wrec_h, Win_h, bc, x_in, Hf, Hh);

    out_kernel<<<dim3(BB), dim3(64), 0, stream>>>(Hf, Wo_w, Wo_b, (float*)d_out);
}

// Round 2
// 3986.919 us; speedup vs baseline: 1.2564x; 1.2564x over previous
//
#include <hip/hip_runtime.h>
#include <hip/hip_fp16.h>

constexpr float ALPHA = 0.9f;
constexpr float DT    = 0.1f;
constexpr int BB   = 256;   // batch
constexpr int NIN  = 784;
constexpr int NN   = 1024;
constexpr int LL   = 4;
constexpr int NOUT = 10;
constexpr int TT   = 100;
constexpr int KXP  = 832;   // xin K padded to multiple of 64

typedef _Float16 f16x8 __attribute__((ext_vector_type(8)));
typedef _Float16 f16x4 __attribute__((ext_vector_type(4)));
typedef float    f32x4 __attribute__((ext_vector_type(4)));

// async global->LDS, 16B per lane. LDS dst must be wave-uniform base (linear fill).
#define GLL16(g, l) __builtin_amdgcn_global_load_lds( \
    (const __attribute__((address_space(1))) unsigned int*)(g), \
    (__attribute__((address_space(3))) unsigned int*)(l), 16, 0, 0)

// ---------------- weight fp32 -> fp16 conversion ----------------
__global__ void wconv_kernel(const float* __restrict__ Wrec,
                             const float* __restrict__ Win,
                             _Float16* __restrict__ Wrec_h,
                             _Float16* __restrict__ Win_h) {
    size_t i = (size_t)blockIdx.x * blockDim.x + threadIdx.x;  // 0 .. 1048575
    float4 r = ((const float4*)Wrec)[i];
    float4 n = ((const float4*)Win)[i];
    f16x4 rh = {(_Float16)r.x, (_Float16)r.y, (_Float16)r.z, (_Float16)r.w};
    f16x4 nh = {(_Float16)n.x, (_Float16)n.y, (_Float16)n.z, (_Float16)n.w};
    ((f16x4*)Wrec_h)[i] = rh;
    ((f16x4*)Win_h)[i]  = nh;
}

// ---------------- X / Wi fp32 -> fp16 with K padded to 832 ----------------
__global__ void prep_kernel(const float* __restrict__ X,
                            const float* __restrict__ Wi_w,
                            _Float16* __restrict__ Xh,
                            _Float16* __restrict__ Wih) {
    int row = blockIdx.x;  // 0..1279
    const float* src;
    _Float16* dst;
    if (row < BB) { src = X + (size_t)row * NIN;        dst = Xh  + (size_t)row * KXP; }
    else          { src = Wi_w + (size_t)(row - BB) * NIN; dst = Wih + (size_t)(row - BB) * KXP; }
    for (int k = threadIdx.x; k < KXP; k += 256)
        dst[k] = (k < NIN) ? (_Float16)src[k] : (_Float16)0.f;
}

// ---------------- combined bias: bc[l] = Wrec_b[l] (+ Win_b[l] for l>0) ----
__global__ void bias_kernel(const float* __restrict__ Win_b,
                            const float* __restrict__ Wrec_b,
                            float* __restrict__ bc) {
    int i = blockIdx.x * 256 + threadIdx.x;  // 0..4095
    int l = i >> 10;
    float v = Wrec_b[i];
    if (l > 0) v += Win_b[i];
    bc[i] = v;
}

// ---------------- x_in = X @ Wi_w^T + Wi_b via fp16 MFMA GEMM ----------------
// BM=128, BN=64, BK=64, 4 waves of 64x32. 32 blocks (2 Mtiles x 16 Ntiles).
__global__ __launch_bounds__(256, 1) void xin_gemm(
    const _Float16* __restrict__ Xh, const _Float16* __restrict__ Wih,
    const float* __restrict__ Wi_b, float* __restrict__ x_in) {
    const int b = blockIdx.x;
    const int mt = b & 1, nt = b >> 1;
    const int row0 = mt * 128, col0 = nt * 64;
    const _Float16* A0 = Xh  + (size_t)row0 * KXP;
    const _Float16* B0 = Wih + (size_t)col0 * KXP;

    __shared__ __align__(16) _Float16 ldsA[2][128 * 64];
    __shared__ __align__(16) _Float16 ldsB[2][64 * 64];

    const int tid = threadIdx.x;
    const int w = tid >> 6, lane = tid & 63;
    const int lm = lane & 15, kg = lane >> 4;
    const int rsub = lane >> 3, cch = lane & 7;
    const int wr = w >> 1, wc = w & 1;

    f32x4 acc[4][2] = {};
    constexpr int NIT = KXP / 64;  // 13

    auto stage = [&](int kk, int buf) {
        int kw = kk * 64;
        #pragma unroll
        for (int i = 0; i < 4; ++i) {
            const _Float16* g = A0 + (size_t)((w * 4 + i) * 8 + rsub) * KXP + kw + ((cch ^ rsub) * 8);
            GLL16(g, &ldsA[buf][(w * 4 + i) * 512]);
        }
        #pragma unroll
        for (int i = 0; i < 2; ++i) {
            const _Float16* g = B0 + (size_t)((w * 2 + i) * 8 + rsub) * KXP + kw + ((cch ^ rsub) * 8);
            GLL16(g, &ldsB[buf][(w * 2 + i) * 512]);
        }
    };

    stage(0, 0);
    __syncthreads();
    for (int kk = 0; kk < NIT; ++kk) {
        int cur = kk & 1;
        if (kk + 1 < NIT) stage(kk + 1, cur ^ 1);
        const _Float16* lA = ldsA[cur];
        const _Float16* lB = ldsB[cur];
        #pragma unroll
        for (int ks = 0; ks < 2; ++ks) {
            f16x8 a[4], bf[2];
            #pragma unroll
            for (int am = 0; am < 4; ++am) {
                int r = wr * 64 + am * 16 + lm;
                a[am] = *(const f16x8*)(lA + r * 64 + ((((ks << 2) | kg) ^ (lm & 7)) * 8));
            }
            #pragma unroll
            for (int bn = 0; bn < 2; ++bn) {
                int c = wc * 32 + bn * 16 + lm;
                bf[bn] = *(const f16x8*)(lB + c * 64 + ((((ks << 2) | kg) ^ (lm & 7)) * 8));
            }
            #pragma unroll
            for (int am = 0; am < 4; ++am)
                #pragma unroll
                for (int bn = 0; bn < 2; ++bn)
                    acc[am][bn] = __builtin_amdgcn_mfma_f32_16x16x32_f16(a[am], bf[bn], acc[am][bn], 0, 0, 0);
        }
        __syncthreads();
    }

    #pragma unroll
    for (int am = 0; am < 4; ++am)
        #pragma unroll
        for (int bn = 0; bn < 2; ++bn)
            #pragma unroll
            for (int r = 0; r < 4; ++r) {
                int row = row0 + wr * 64 + am * 16 + kg * 4 + r;
                int col = col0 + wc * 32 + bn * 16 + lm;
                x_in[(size_t)row * NN + col] = acc[am][bn][r] + Wi_b[col];
            }
}

// ---------------- wavefront stage GEMM ----------------
// Hf: [4][256][1024] fp32 state (in-place), Hh: [2][4][256][1024] fp16 shadow.
// layer l at t=s-l: pre = h_l(t-1)@Wrec^T (+ h_{l-1}(t)@Win^T for l>0) + bias (+x_in for l0)
// BM=128, BN=64, BK=64; virtual K = 2048 for l>0 (phase switch at kk=16).
__global__ __launch_bounds__(256, 1) void stage_kernel(
    int s,
    const _Float16* __restrict__ Wrec_h,
    const _Float16* __restrict__ Win_h,
    const float* __restrict__ bc,
    const float* __restrict__ x_in,
    float* __restrict__ Hf,
    _Float16* __restrict__ Hh) {
    const int b = blockIdx.x;
    const int l = (b & 7) >> 1;               // layer -> XCD pair
    const int t = s - l;
    if (t < 0 || t >= TT) return;
    const int j  = (b & 1) | ((b >> 3) << 1); // 0..31 tile within layer
    const int mt = j & 1, nt = j >> 1;
    const int row0 = mt * 128, col0 = nt * 64;

    const int src = t & 1, dst = src ^ 1;
    const size_t HSZ = (size_t)BB * NN;

    const _Float16* A0 = Hh + ((size_t)src * LL + l) * HSZ + (size_t)row0 * NN;
    const _Float16* B0 = Wrec_h + (size_t)l * NN * NN + (size_t)col0 * NN;
    const _Float16* A1 = A0;
    const _Float16* B1 = B0;
    int niter = 16;
    if (l > 0) {
        A1 = Hh + ((size_t)dst * LL + (l - 1)) * HSZ + (size_t)row0 * NN;
        B1 = Win_h + (size_t)l * NN * NN + (size_t)col0 * NN;
        niter = 32;
    }

    __shared__ __align__(16) _Float16 ldsA[2][128 * 64];
    __shared__ __align__(16) _Float16 ldsB[2][64 * 64];

    const int tid = threadIdx.x;
    const int w = tid >> 6, lane = tid & 63;
    const int lm = lane & 15, kg = lane >> 4;
    const int rsub = lane >> 3, cch = lane & 7;
    const int wr = w >> 1, wc = w & 1;

    f32x4 acc[4][2] = {};

    auto stage = [&](int kk, int buf) {
        const _Float16 *Ap, *Bp;
        int kw;
        if (kk < 16) { Ap = A0; Bp = B0; kw = kk * 64; }
        else         { Ap = A1; Bp = B1; kw = (kk - 16) * 64; }
        #pragma unroll
        for (int i = 0; i < 4; ++i) {
            const _Float16* g = Ap + (size_t)((w * 4 + i) * 8 + rsub) * NN + kw + ((cch ^ rsub) * 8);
            GLL16(g, &ldsA[buf][(w * 4 + i) * 512]);
        }
        #pragma unroll
        for (int i = 0; i < 2; ++i) {
            const _Float16* g = Bp + (size_t)((w * 2 + i) * 8 + rsub) * NN + kw + ((cch ^ rsub) * 8);
            GLL16(g, &ldsB[buf][(w * 2 + i) * 512]);
        }
    };

    stage(0, 0);
    __syncthreads();
    for (int kk = 0; kk < niter; ++kk) {
        int cur = kk & 1;
        if (kk + 1 < niter) stage(kk + 1, cur ^ 1);
        const _Float16* lA = ldsA[cur];
        const _Float16* lB = ldsB[cur];
        #pragma unroll
        for (int ks = 0; ks < 2; ++ks) {
            f16x8 a[4], bf[2];
            #pragma unroll
            for (int am = 0; am < 4; ++am) {
                int r = wr * 64 + am * 16 + lm;
                a[am] = *(const f16x8*)(lA + r * 64 + ((((ks << 2) | kg) ^ (lm & 7)) * 8));
            }
            #pragma unroll
            for (int bn = 0; bn < 2; ++bn) {
                int c = wc * 32 + bn * 16 + lm;
                bf[bn] = *(const f16x8*)(lB + c * 64 + ((((ks << 2) | kg) ^ (lm & 7)) * 8));
            }
            #pragma unroll
            for (int am = 0; am < 4; ++am)
                #pragma unroll
                for (int bn = 0; bn < 2; ++bn)
                    acc[am][bn] = __builtin_amdgcn_mfma_f32_16x16x32_f16(a[am], bf[bn], acc[am][bn], 0, 0, 0);
        }
        __syncthreads();
    }

    // epilogue: h' = h + DT*(-ALPHA*h + sin(pre))
    const float* bcl = bc + l * NN;
    float* Hfl = Hf + (size_t)l * HSZ;
    _Float16* Hhd = Hh + ((size_t)dst * LL + l) * HSZ;
    #pragma unroll
    for (int am = 0; am < 4; ++am)
        #pragma unroll
        for (int bn = 0; bn < 2; ++bn)
            #pragma unroll
            for (int r = 0; r < 4; ++r) {
                int row = row0 + wr * 64 + am * 16 + kg * 4 + r;
                int col = col0 + wc * 32 + bn * 16 + lm;
                size_t idx = (size_t)row * NN + col;
                float pre = acc[am][bn][r] + bcl[col];
                if (l == 0) pre += x_in[idx];
                float hold = Hfl[idx];
                float hnew = hold + DT * (-ALPHA * hold + __sinf(pre));
                Hfl[idx] = hnew;
                Hhd[idx] = (_Float16)hnew;
            }
}

// ---------------- out = h[3] @ Wo^T + Wo_b  (fp32) ----------------
__global__ void out_kernel(const float* __restrict__ Hf,
                           const float* __restrict__ Wo_w,
                           const float* __restrict__ Wo_b,
                           float* __restrict__ out) {
    const float* h = Hf + (size_t)3 * BB * NN + (size_t)blockIdx.x * NN;
    int lane = threadIdx.x;
    for (int j = 0; j < NOUT; ++j) {
        const float* wv = Wo_w + (size_t)j * NN;
        float sum = 0.f;
        for (int k = lane; k < NN; k += 64) sum += h[k] * wv[k];
        #pragma unroll
        for (int off = 32; off; off >>= 1) sum += __shfl_down(sum, off);
        if (lane == 0) out[blockIdx.x * NOUT + j] = sum + Wo_b[j];
    }
}

extern "C" void kernel_launch(void* const* d_in, const int* in_sizes, int n_in,
                              void* d_out, int out_size, void* d_ws, size_t ws_size,
                              hipStream_t stream) {
    const float* X      = (const float*)d_in[0];
    const float* Wi_w   = (const float*)d_in[1];
    const float* Wi_b   = (const float*)d_in[2];
    const float* Win_w  = (const float*)d_in[3];
    const float* Win_b  = (const float*)d_in[4];
    const float* Wrec_w = (const float*)d_in[5];
    const float* Wrec_b = (const float*)d_in[6];
    const float* Wo_w   = (const float*)d_in[7];
    const float* Wo_b   = (const float*)d_in[8];

    char* ws = (char*)d_ws;
    _Float16* Wrec_h = (_Float16*)(ws);                                  // 8 MB
    _Float16* Win_h  = (_Float16*)(ws + (size_t)(8u  << 20));            // 8 MB
    float*    Hf     = (float*)   (ws + (size_t)(16u << 20));            // 4 MB
    _Float16* Hh     = (_Float16*)(ws + (size_t)(20u << 20));            // 4 MB
    float*    x_in   = (float*)   (ws + (size_t)(24u << 20));            // 1 MB
    float*    bc     = (float*)   (ws + (size_t)(25u << 20));            // 16 KB
    _Float16* Xh     = (_Float16*)(ws + (size_t)(25u << 20) + 65536);    // 416 KB
    _Float16* Wih    = (_Float16*)(ws + (size_t)(26u << 20));            // 1.63 MB

    wconv_kernel<<<4096, 256, 0, stream>>>(Wrec_w, Win_w, Wrec_h, Win_h);
    prep_kernel<<<BB + NN, 256, 0, stream>>>(X, Wi_w, Xh, Wih);
    bias_kernel<<<16, 256, 0, stream>>>(Win_b, Wrec_b, bc);
    hipMemsetAsync(Hf, 0, (size_t)LL * BB * NN * sizeof(float), stream);
    hipMemsetAsync(Hh, 0, (size_t)LL * BB * NN * sizeof(_Float16), stream);  // parity 0
    xin_gemm<<<32, 256, 0, stream>>>(Xh, Wih, Wi_b, x_in);

    for (int s = 0; s <= TT + LL - 2; ++s)
        stage_kernel<<<128, 256, 0, stream>>>(s, Wrec_h, Win_h, bc, x_in, Hf, Hh);

    out_kernel<<<BB, 64, 0, stream>>>(Hf, Wo_w, Wo_b, (float*)d_out);
}